// Round 1
// baseline (411.653 us; speedup 1.0000x reference)
//
#include <hip/hip_runtime.h>
#include <math.h>

#define T_TOKENS 8192
#define NEXP 256
#define DIM 7168
#define NSPLIT 4
#define KSPL (DIM / NSPLIT)   // 1792
#define BM 128
#define BN 128
#define BK 32
#define NEG_INF (-3.0e38f)

// ---------------- GEMM: partial logits, split-K ----------------
// grid (M/BM=64, N/BN=2, NSPLIT=4), block 256 (16x16 threads, 8x8 micro-tile)
__global__ __launch_bounds__(256) void gemm_partial(const float* __restrict__ x,
                                                    const float* __restrict__ w,
                                                    float* __restrict__ part) {
    __shared__ float As[BK][BM + 4];   // pitch 132 floats: 16B-aligned rows, breaks write conflicts
    __shared__ float Bs[BK][BN + 4];

    const int tid = threadIdx.x;
    const int bm = blockIdx.x;   // 0..63
    const int bn = blockIdx.y;   // 0..1
    const int bz = blockIdx.z;   // 0..3

    const float* Ag = x + (size_t)bm * BM * DIM + (size_t)bz * KSPL;
    const float* Bg = w + (size_t)bn * BN * DIM + (size_t)bz * KSPL;

    const int lr = tid >> 3;          // 0..31 (row within 32-row chunk)
    const int lk = (tid & 7) * 4;     // 0,4,...,28 (k offset, float4)

    const int ty = tid >> 4;          // 0..15
    const int tx = tid & 15;          // 0..15

    float acc[8][8];
#pragma unroll
    for (int i = 0; i < 8; i++)
#pragma unroll
        for (int j = 0; j < 8; j++) acc[i][j] = 0.0f;

    for (int kc = 0; kc < KSPL; kc += BK) {
        // stage A: 128 rows x 32 k
#pragma unroll
        for (int j = 0; j < 4; j++) {
            const float4 v = *(const float4*)(Ag + (size_t)(lr + j * 32) * DIM + kc + lk);
            As[lk + 0][lr + j * 32] = v.x;
            As[lk + 1][lr + j * 32] = v.y;
            As[lk + 2][lr + j * 32] = v.z;
            As[lk + 3][lr + j * 32] = v.w;
        }
        // stage B: 128 rows x 32 k
#pragma unroll
        for (int j = 0; j < 4; j++) {
            const float4 v = *(const float4*)(Bg + (size_t)(lr + j * 32) * DIM + kc + lk);
            Bs[lk + 0][lr + j * 32] = v.x;
            Bs[lk + 1][lr + j * 32] = v.y;
            Bs[lk + 2][lr + j * 32] = v.z;
            Bs[lk + 3][lr + j * 32] = v.w;
        }
        __syncthreads();

#pragma unroll 8
        for (int k = 0; k < BK; k++) {
            float a[8], b[8];
            *(float4*)&a[0] = *(const float4*)&As[k][ty * 4];
            *(float4*)&a[4] = *(const float4*)&As[k][ty * 4 + 64];
            *(float4*)&b[0] = *(const float4*)&Bs[k][tx * 4];
            *(float4*)&b[4] = *(const float4*)&Bs[k][tx * 4 + 64];
#pragma unroll
            for (int i = 0; i < 8; i++)
#pragma unroll
                for (int j = 0; j < 8; j++)
                    acc[i][j] = fmaf(a[i], b[j], acc[i][j]);
        }
        __syncthreads();
    }

    // store partial logits: part[bz][token][expert]
    float* P = part + ((size_t)bz * T_TOKENS + (size_t)bm * BM) * NEXP + bn * BN;
#pragma unroll
    for (int i = 0; i < 8; i++) {
        const int r = ty * 4 + (i & 3) + ((i >> 2) << 6);
        float4 v0 = make_float4(acc[i][0], acc[i][1], acc[i][2], acc[i][3]);
        float4 v1 = make_float4(acc[i][4], acc[i][5], acc[i][6], acc[i][7]);
        *(float4*)(P + (size_t)r * NEXP + tx * 4) = v0;
        *(float4*)(P + (size_t)r * NEXP + tx * 4 + 64) = v1;
    }
}

// ---------------- Routing: one wave per token ----------------
// block 256 (4 tokens), grid 2048
__global__ __launch_bounds__(256) void routing_kernel(const float* __restrict__ part,
                                                      const float* __restrict__ bias,
                                                      float* __restrict__ out) {
    const int lane = threadIdx.x & 63;
    const int t = blockIdx.x * 4 + (threadIdx.x >> 6);

    // sum split-K partials: lane holds experts lane*4 .. lane*4+3
    float4 z = make_float4(0.f, 0.f, 0.f, 0.f);
#pragma unroll
    for (int s = 0; s < NSPLIT; s++) {
        const float4 v = *((const float4*)(part + ((size_t)s * T_TOKENS + t) * NEXP) + lane);
        z.x += v.x; z.y += v.y; z.z += v.z; z.w += v.w;
    }
    // sigmoid -> original scores
    const float s0 = 1.0f / (1.0f + expf(-z.x));
    const float s1 = 1.0f / (1.0f + expf(-z.y));
    const float s2 = 1.0f / (1.0f + expf(-z.z));
    const float s3 = 1.0f / (1.0f + expf(-z.w));
    // biased scores
    const float4 bv = *((const float4*)bias + lane);
    float sb0 = s0 + bv.x, sb1 = s1 + bv.y, sb2 = s2 + bv.z, sb3 = s3 + bv.w;

    // ---- group score = sum of top-2 biased scores within 32-expert group (8 lanes) ----
    float m1, m2;
    m1 = sb0; m2 = NEG_INF;
    if (sb1 > m1) { m2 = m1; m1 = sb1; } else if (sb1 > m2) m2 = sb1;
    if (sb2 > m1) { m2 = m1; m1 = sb2; } else if (sb2 > m2) m2 = sb2;
    if (sb3 > m1) { m2 = m1; m1 = sb3; } else if (sb3 > m2) m2 = sb3;
#pragma unroll
    for (int off = 1; off < 8; off <<= 1) {
        const float om1 = __shfl_xor(m1, off);
        const float om2 = __shfl_xor(m2, off);
        const float hi = fmaxf(m1, om1);
        const float lo = fminf(m1, om1);
        m2 = fmaxf(lo, fmaxf(m2, om2));
        m1 = hi;
    }
    const float gs = m1 + m2;

    // broadcast all 8 group scores
    const float g0 = __shfl(gs, 0),  g1 = __shfl(gs, 8),  g2 = __shfl(gs, 16), g3 = __shfl(gs, 24);
    const float g4 = __shfl(gs, 32), g5 = __shfl(gs, 40), g6 = __shfl(gs, 48), g7 = __shfl(gs, 56);

    // ---- stable top-4 groups (strict >, ascending index = lax.top_k tie-break) ----
    float t1 = NEG_INF, t2 = NEG_INF, t3 = NEG_INF, t4 = NEG_INF;
    int i1 = 0, i2 = 0, i3 = 0, i4 = 0;
#define INS4(v, gi)                                                         \
    {                                                                       \
        if (v > t1)      { t4=t3;i4=i3; t3=t2;i3=i2; t2=t1;i2=i1; t1=v;i1=gi; } \
        else if (v > t2) { t4=t3;i4=i3; t3=t2;i3=i2; t2=v;i2=gi; }          \
        else if (v > t3) { t4=t3;i4=i3; t3=v;i3=gi; }                       \
        else if (v > t4) { t4=v;i4=gi; }                                    \
    }
    INS4(g0, 0) INS4(g1, 1) INS4(g2, 2) INS4(g3, 3)
    INS4(g4, 4) INS4(g5, 5) INS4(g6, 6) INS4(g7, 7)
#undef INS4
    const int keepmask = (1 << i1) | (1 << i2) | (1 << i3) | (1 << i4);

    // mask out experts of dropped groups
    const int g = lane >> 3;
    if (!((keepmask >> g) & 1)) { sb0 = NEG_INF; sb1 = NEG_INF; sb2 = NEG_INF; sb3 = NEG_INF; }

    // ---- global stable top-8 over masked biased scores ----
    float wv[8];
    int wi[8];
    float wsum = 0.0f;
#pragma unroll
    for (int r = 0; r < 8; r++) {
        float bvv = sb0;
        int bii = (lane << 2);
        if (sb1 > bvv) { bvv = sb1; bii = (lane << 2) | 1; }
        if (sb2 > bvv) { bvv = sb2; bii = (lane << 2) | 2; }
        if (sb3 > bvv) { bvv = sb3; bii = (lane << 2) | 3; }
#pragma unroll
        for (int off = 1; off < 64; off <<= 1) {
            const float ov = __shfl_xor(bvv, off);
            const int oi = __shfl_xor(bii, off);
            if (ov > bvv || (ov == bvv && oi < bii)) { bvv = ov; bii = oi; }
        }
        // gather the winner's ORIGINAL (unbiased) score
        const int sl = bii & 3;
        const float cand = (sl == 0) ? s0 : (sl == 1) ? s1 : (sl == 2) ? s2 : s3;
        const float ow = __shfl(cand, bii >> 2);
        wv[r] = ow;
        wi[r] = bii;
        wsum += ow;
        // invalidate the winner slot on its owner lane
        if ((bii >> 2) == lane) {
            if (sl == 0) sb0 = NEG_INF;
            else if (sl == 1) sb1 = NEG_INF;
            else if (sl == 2) sb2 = NEG_INF;
            else sb3 = NEG_INF;
        }
    }
    const float scale = 2.5f / wsum;
    if (lane == 0) {
        float* ow8 = out + (size_t)t * 8;
        float* oi8 = out + (size_t)T_TOKENS * 8 + (size_t)t * 8;
#pragma unroll
        for (int r = 0; r < 8; r++) {
            ow8[r] = wv[r] * scale;
            oi8[r] = (float)wi[r];
        }
    }
}

extern "C" void kernel_launch(void* const* d_in, const int* in_sizes, int n_in,
                              void* d_out, int out_size, void* d_ws, size_t ws_size,
                              hipStream_t stream) {
    const float* x = (const float*)d_in[0];
    const float* w = (const float*)d_in[1];
    const float* bias = (const float*)d_in[2];
    float* part = (float*)d_ws;   // NSPLIT * 8192 * 256 floats = 32 MiB

    dim3 grid_g(T_TOKENS / BM, NEXP / BN, NSPLIT);
    gemm_partial<<<grid_g, 256, 0, stream>>>(x, w, part);

    routing_kernel<<<T_TOKENS / 4, 256, 0, stream>>>(part, bias, (float*)d_out);
}

// Round 3
// 143.137 us; speedup vs baseline: 2.8759x; 2.8759x over previous
//
#include <hip/hip_runtime.h>
#include <math.h>

#define T_TOKENS 8192
#define NEXP 256
#define DIM 7168
#define NEG_INF (-3.0e38f)

typedef _Float16 f16;
typedef _Float16 f16x8 __attribute__((ext_vector_type(8)));
typedef __fp16 h16x2 __attribute__((ext_vector_type(2)));   // cvt_pkrtz result type
typedef float f32x4 __attribute__((ext_vector_type(4)));

#define AS1 __attribute__((address_space(1)))
#define AS3 __attribute__((address_space(3)))

// ws layout: [W0 plane f16][W1 plane f16][part f32 (nsplit x T x E)]
#define WPLANE_BYTES (NEXP * DIM * 2)          // 3,670,016
#define PART_OFF (2 * WPLANE_BYTES)            // 7,340,032
#define UNSCALE 5.9604644775390625e-8f         // 2^-24 exact

// ---------------- prologue: w (f32) -> two scaled f16 planes ----------------
// w0 = f16(w*4096) RTZ, w1 = f16(w*4096 - w0) RTZ. Residual split is exact.
__global__ __launch_bounds__(256) void wconvert(const float* __restrict__ w,
                                                f16* __restrict__ w0p,
                                                f16* __restrict__ w1p) {
    const int i = (blockIdx.x * 256 + threadIdx.x) * 8;
    const f32x4 u0 = *(const f32x4*)(w + i);
    const f32x4 u1 = *(const f32x4*)(w + i + 4);
    float c[8] = {u0[0]*4096.f, u0[1]*4096.f, u0[2]*4096.f, u0[3]*4096.f,
                  u1[0]*4096.f, u1[1]*4096.f, u1[2]*4096.f, u1[3]*4096.f};
    f16x8 h, g;
#pragma unroll
    for (int j = 0; j < 4; ++j) {
        h16x2 hp = __builtin_amdgcn_cvt_pkrtz(c[2*j], c[2*j+1]);
        float r0 = c[2*j]   - (float)hp[0];
        float r1 = c[2*j+1] - (float)hp[1];
        h16x2 gp = __builtin_amdgcn_cvt_pkrtz(r0, r1);
        h[2*j] = (f16)hp[0]; h[2*j+1] = (f16)hp[1];
        g[2*j] = (f16)gp[0]; g[2*j+1] = (f16)gp[1];
    }
    *(f16x8*)(w0p + i) = h;
    *(f16x8*)(w1p + i) = g;
}

// ---------------- GEMM: logits*2^24 via 4x f16 MFMA product classes ----------------
// grid (64, 2, nsplit), block 256 (4 waves, 2x2 wave grid, 64x64 wave tile)
// LDS: A f32 [128][64] (32KB, 16B-unit XOR-(row&7) swizzle) + W f16 2 planes [128][64] (32KB)
__global__ __launch_bounds__(256, 2) void gemm_f16split(
    const float* __restrict__ x, const f16* __restrict__ w0,
    float* __restrict__ part, int ksplit) {
    __shared__ char smem[65536];
    const int tid = threadIdx.x;
    const int lane = tid & 63;
    const int wv = tid >> 6;        // wave 0..3
    const int bm = blockIdx.x, bn = blockIdx.y, bz = blockIdx.z;
    const int wr = wv >> 1, wc = wv & 1;
    const int l15 = lane & 15, l7 = lane & 7, q4 = lane >> 4;

    const char* xc = (const char*)x;
    const char* wc0 = (const char*)w0;   // w1 plane = +WPLANE_BYTES

    // staging: per-lane 32-bit source offsets, wave-uniform LDS dests
    int aoff[8], woff[8], ldsA[8], ldsW[8];
#pragma unroll
    for (int i = 0; i < 8; ++i) {
        const int inst = wv * 8 + i;
        // A: 1KB chunk inst covers rows inst*4 + (lane>>4), 16B unit t = lane&15
        const int arow = inst * 4 + (lane >> 4);
        const int t = lane & 15;
        aoff[i] = (int)((((size_t)(bm * 128 + arow) * DIM + (size_t)bz * ksplit) * 4)
                        + (size_t)((t ^ (arow & 7)) * 16));
        ldsA[i] = inst * 1024;
        // W: plane inst>>4, rows (inst&15)*8 + (lane>>3), 16B unit u = lane&7
        const int wrow = (inst & 15) * 8 + (lane >> 3);
        woff[i] = (inst >> 4) * WPLANE_BYTES
                + (int)((((size_t)(bn * 128 + wrow) * DIM + (size_t)bz * ksplit) * 2)
                        + (size_t)(((lane & 7) ^ (wrow & 7)) * 16));
        ldsW[i] = 32768 + inst * 1024;
    }

    // fragment-read lane constants
    int offA[2][2], offB[2];
#pragma unroll
    for (int s = 0; s < 2; ++s) {
        offA[s][0] = ((2 * (s * 4 + q4) + 0) ^ l7) * 16;
        offA[s][1] = ((2 * (s * 4 + q4) + 1) ^ l7) * 16;
        offB[s] = ((s * 4 + q4) ^ l7) * 16;
    }
    const int rowA = (wr * 64 + l15) * 256;
    const int rowB = 32768 + (wc * 64 + l15) * 128;

    f32x4 acc[4][4];
#pragma unroll
    for (int m = 0; m < 4; ++m)
#pragma unroll
        for (int n = 0; n < 4; ++n) acc[m][n] = (f32x4){0.f, 0.f, 0.f, 0.f};

    const int niter = ksplit >> 6;
    for (int kt = 0; kt < niter; ++kt) {
#pragma unroll
        for (int i = 0; i < 8; ++i)
            __builtin_amdgcn_global_load_lds((const AS1 void*)(xc + aoff[i]),
                                             (AS3 void*)(smem + ldsA[i]), 16, 0, 0);
#pragma unroll
        for (int i = 0; i < 8; ++i)
            __builtin_amdgcn_global_load_lds((const AS1 void*)(wc0 + woff[i]),
                                             (AS3 void*)(smem + ldsW[i]), 16, 0, 0);
#pragma unroll
        for (int i = 0; i < 8; ++i) { aoff[i] += 256; woff[i] += 128; }
        __syncthreads();   // drains vmcnt -> LDS tiles ready

#pragma unroll
        for (int s = 0; s < 2; ++s) {
            f16x8 bf0[4], bf1[4];
#pragma unroll
            for (int n = 0; n < 4; ++n) {
                bf0[n] = *(const f16x8*)(smem + rowB + n * 2048 + offB[s]);
                bf1[n] = *(const f16x8*)(smem + rowB + 16384 + n * 2048 + offB[s]);
            }
#pragma unroll
            for (int m = 0; m < 4; ++m) {
                const f32x4 v0 = *(const f32x4*)(smem + rowA + m * 4096 + offA[s][0]);
                const f32x4 v1 = *(const f32x4*)(smem + rowA + m * 4096 + offA[s][1]);
                float c[8] = {v0[0]*4096.f, v0[1]*4096.f, v0[2]*4096.f, v0[3]*4096.f,
                              v1[0]*4096.f, v1[1]*4096.f, v1[2]*4096.f, v1[3]*4096.f};
                f16x8 a0, a1;
#pragma unroll
                for (int j = 0; j < 4; ++j) {
                    h16x2 hp = __builtin_amdgcn_cvt_pkrtz(c[2*j], c[2*j+1]);
                    float r0 = c[2*j]   - (float)hp[0];
                    float r1 = c[2*j+1] - (float)hp[1];
                    h16x2 gp = __builtin_amdgcn_cvt_pkrtz(r0, r1);
                    a0[2*j] = (f16)hp[0]; a0[2*j+1] = (f16)hp[1];
                    a1[2*j] = (f16)gp[0]; a1[2*j+1] = (f16)gp[1];
                }
#pragma unroll
                for (int n = 0; n < 4; ++n) {
                    acc[m][n] = __builtin_amdgcn_mfma_f32_16x16x32_f16(a0, bf0[n], acc[m][n], 0, 0, 0);
                    acc[m][n] = __builtin_amdgcn_mfma_f32_16x16x32_f16(a1, bf0[n], acc[m][n], 0, 0, 0);
                    acc[m][n] = __builtin_amdgcn_mfma_f32_16x16x32_f16(a0, bf1[n], acc[m][n], 0, 0, 0);
                    acc[m][n] = __builtin_amdgcn_mfma_f32_16x16x32_f16(a1, bf1[n], acc[m][n], 0, 0, 0);
                }
            }
        }
        __syncthreads();   // compute done before next overwrite
    }

    // epilogue: store raw scaled partials (routing applies 2^-24)
    float* P = part + (size_t)bz * T_TOKENS * NEXP;
    const int orow = bm * 128 + wr * 64 + (lane >> 4) * 4;
    const int ocol = bn * 128 + wc * 64 + l15;
#pragma unroll
    for (int m = 0; m < 4; ++m)
#pragma unroll
        for (int n = 0; n < 4; ++n)
#pragma unroll
            for (int r = 0; r < 4; ++r)
                P[(size_t)(orow + m * 16 + r) * NEXP + ocol + n * 16] = acc[m][n][r];
}

// ---------------- Routing: one wave per token (identical logic to R1) ----------------
__global__ __launch_bounds__(256) void routing_kernel(const float* __restrict__ part,
                                                      const float* __restrict__ bias,
                                                      float* __restrict__ out, int nsplit) {
    const int lane = threadIdx.x & 63;
    const int t = blockIdx.x * 4 + (threadIdx.x >> 6);

    f32x4 z = {0.f, 0.f, 0.f, 0.f};
    for (int s = 0; s < nsplit; ++s) {
        const f32x4 v = *((const f32x4*)(part + ((size_t)s * T_TOKENS + t) * NEXP) + lane);
        z[0] += v[0]; z[1] += v[1]; z[2] += v[2]; z[3] += v[3];
    }
    const float s0 = 1.0f / (1.0f + expf(-z[0] * UNSCALE));
    const float s1 = 1.0f / (1.0f + expf(-z[1] * UNSCALE));
    const float s2 = 1.0f / (1.0f + expf(-z[2] * UNSCALE));
    const float s3 = 1.0f / (1.0f + expf(-z[3] * UNSCALE));
    const f32x4 bv = *((const f32x4*)bias + lane);
    float sb0 = s0 + bv[0], sb1 = s1 + bv[1], sb2 = s2 + bv[2], sb3 = s3 + bv[3];

    float m1, m2;
    m1 = sb0; m2 = NEG_INF;
    if (sb1 > m1) { m2 = m1; m1 = sb1; } else if (sb1 > m2) m2 = sb1;
    if (sb2 > m1) { m2 = m1; m1 = sb2; } else if (sb2 > m2) m2 = sb2;
    if (sb3 > m1) { m2 = m1; m1 = sb3; } else if (sb3 > m2) m2 = sb3;
#pragma unroll
    for (int off = 1; off < 8; off <<= 1) {
        const float om1 = __shfl_xor(m1, off);
        const float om2 = __shfl_xor(m2, off);
        const float hi = fmaxf(m1, om1);
        const float lo = fminf(m1, om1);
        m2 = fmaxf(lo, fmaxf(m2, om2));
        m1 = hi;
    }
    const float gs = m1 + m2;

    const float g0 = __shfl(gs, 0),  g1 = __shfl(gs, 8),  g2 = __shfl(gs, 16), g3 = __shfl(gs, 24);
    const float g4 = __shfl(gs, 32), g5 = __shfl(gs, 40), g6 = __shfl(gs, 48), g7 = __shfl(gs, 56);

    float t1 = NEG_INF, t2 = NEG_INF, t3 = NEG_INF, t4 = NEG_INF;
    int i1 = 0, i2 = 0, i3 = 0, i4 = 0;
#define INS4(v, gi)                                                         \
    {                                                                       \
        if (v > t1)      { t4=t3;i4=i3; t3=t2;i3=i2; t2=t1;i2=i1; t1=v;i1=gi; } \
        else if (v > t2) { t4=t3;i4=i3; t3=t2;i3=i2; t2=v;i2=gi; }          \
        else if (v > t3) { t4=t3;i4=i3; t3=v;i3=gi; }                       \
        else if (v > t4) { t4=v;i4=gi; }                                    \
    }
    INS4(g0, 0) INS4(g1, 1) INS4(g2, 2) INS4(g3, 3)
    INS4(g4, 4) INS4(g5, 5) INS4(g6, 6) INS4(g7, 7)
#undef INS4
    const int keepmask = (1 << i1) | (1 << i2) | (1 << i3) | (1 << i4);

    const int g = lane >> 3;
    if (!((keepmask >> g) & 1)) { sb0 = NEG_INF; sb1 = NEG_INF; sb2 = NEG_INF; sb3 = NEG_INF; }

    float wval[8];
    int wi[8];
    float wsum = 0.0f;
#pragma unroll
    for (int r = 0; r < 8; r++) {
        float bvv = sb0;
        int bii = (lane << 2);
        if (sb1 > bvv) { bvv = sb1; bii = (lane << 2) | 1; }
        if (sb2 > bvv) { bvv = sb2; bii = (lane << 2) | 2; }
        if (sb3 > bvv) { bvv = sb3; bii = (lane << 2) | 3; }
#pragma unroll
        for (int off = 1; off < 64; off <<= 1) {
            const float ov = __shfl_xor(bvv, off);
            const int oi = __shfl_xor(bii, off);
            if (ov > bvv || (ov == bvv && oi < bii)) { bvv = ov; bii = oi; }
        }
        const int sl = bii & 3;
        const float cand = (sl == 0) ? s0 : (sl == 1) ? s1 : (sl == 2) ? s2 : s3;
        const float ow = __shfl(cand, bii >> 2);
        wval[r] = ow;
        wi[r] = bii;
        wsum += ow;
        if ((bii >> 2) == lane) {
            if (sl == 0) sb0 = NEG_INF;
            else if (sl == 1) sb1 = NEG_INF;
            else if (sl == 2) sb2 = NEG_INF;
            else sb3 = NEG_INF;
        }
    }
    const float scale = 2.5f / wsum;
    if (lane == 0) {
        float* ow8 = out + (size_t)t * 8;
        float* oi8 = out + (size_t)T_TOKENS * 8 + (size_t)t * 8;
#pragma unroll
        for (int r = 0; r < 8; r++) {
            ow8[r] = wval[r] * scale;
            oi8[r] = (float)wi[r];
        }
    }
}

extern "C" void kernel_launch(void* const* d_in, const int* in_sizes, int n_in,
                              void* d_out, int out_size, void* d_ws, size_t ws_size,
                              hipStream_t stream) {
    const float* x = (const float*)d_in[0];
    const float* w = (const float*)d_in[1];
    const float* bias = (const float*)d_in[2];

    f16* w0 = (f16*)d_ws;
    f16* w1 = (f16*)((char*)d_ws + WPLANE_BYTES);
    float* part = (float*)((char*)d_ws + PART_OFF);

    // NSPLIT=4 needs 40.9 MB of ws; R1 only proved ws >= 33.55 MB -> fallback to 2.
    const size_t need4 = (size_t)PART_OFF + 4ull * T_TOKENS * NEXP * 4;
    const int nsplit = (ws_size >= need4) ? 4 : 2;
    const int ksplit = DIM / nsplit;

    wconvert<<<NEXP * DIM / (256 * 8), 256, 0, stream>>>(w, w0, w1);
    gemm_f16split<<<dim3(64, 2, nsplit), 256, 0, stream>>>(x, w0, part, ksplit);
    routing_kernel<<<T_TOKENS / 4, 256, 0, stream>>>(part, bias, (float*)d_out, nsplit);
}

// Round 4
// 141.470 us; speedup vs baseline: 2.9098x; 1.0118x over previous
//
#include <hip/hip_runtime.h>
#include <math.h>

#define T_TOKENS 8192
#define NEXP 256
#define DIM 7168
#define NEG_INF (-3.0e38f)

typedef _Float16 f16;
typedef _Float16 f16x8 __attribute__((ext_vector_type(8)));
typedef __fp16 h16x2 __attribute__((ext_vector_type(2)));   // cvt_pkrtz result type
typedef float f32x4 __attribute__((ext_vector_type(4)));

#define AS1 __attribute__((address_space(1)))
#define AS3 __attribute__((address_space(3)))

// ws layout: [W0 plane f16][W1 plane f16][part f32 (nsplit x T x E)]
#define WPLANE_BYTES (NEXP * DIM * 2)          // 3,670,016
#define PART_OFF (2 * WPLANE_BYTES)            // 7,340,032
#define UNSCALE 5.9604644775390625e-8f         // 2^-24 exact

// ---------------- prologue: w (f32) -> two scaled f16 planes ----------------
__global__ __launch_bounds__(256) void wconvert(const float* __restrict__ w,
                                                f16* __restrict__ w0p,
                                                f16* __restrict__ w1p) {
    const int i = (blockIdx.x * 256 + threadIdx.x) * 8;
    const f32x4 u0 = *(const f32x4*)(w + i);
    const f32x4 u1 = *(const f32x4*)(w + i + 4);
    float c[8] = {u0[0]*4096.f, u0[1]*4096.f, u0[2]*4096.f, u0[3]*4096.f,
                  u1[0]*4096.f, u1[1]*4096.f, u1[2]*4096.f, u1[3]*4096.f};
    f16x8 h, g;
#pragma unroll
    for (int j = 0; j < 4; ++j) {
        h16x2 hp = __builtin_amdgcn_cvt_pkrtz(c[2*j], c[2*j+1]);
        float r0 = c[2*j]   - (float)hp[0];
        float r1 = c[2*j+1] - (float)hp[1];
        h16x2 gp = __builtin_amdgcn_cvt_pkrtz(r0, r1);
        h[2*j] = (f16)hp[0]; h[2*j+1] = (f16)hp[1];
        g[2*j] = (f16)gp[0]; g[2*j+1] = (f16)gp[1];
    }
    *(f16x8*)(w0p + i) = h;
    *(f16x8*)(w1p + i) = g;
}

// ---------------- GEMM: double-buffered BK=32, counted vmcnt ----------------
// grid (64, 2, nsplit), block 256 (4 waves, 2x2 wave grid, 64x64 wave tile)
// LDS per stage (32KB): A f32 [128 rows][32 k] swizzled XOR(row&7) on 16B units,
//                       W f16 2 planes [128 rows][32 k] swizzled XOR((row>>1)&3)
__global__ __launch_bounds__(256, 2) void gemm_f16split_db(
    const float* __restrict__ x, const f16* __restrict__ w0,
    float* __restrict__ part, int ksplit) {
    __shared__ char smem[65536];
    const int tid = threadIdx.x;
    const int lane = tid & 63;
    const int wv = tid >> 6;
    const int bm = blockIdx.x, bn = blockIdx.y, bz = blockIdx.z;
    const int wr = wv >> 1, wc = wv & 1;
    const int l15 = lane & 15, q4 = lane >> 4;

    const char* xc = (const char*)x;
    const char* wcp = (const char*)w0;   // w1 plane at +WPLANE_BYTES

    // ---- staging offsets: 4 A-insts + 4 W-insts per wave per K-step ----
    int aoff[4], woff[4], ldsA[4], ldsW[4];
#pragma unroll
    for (int i = 0; i < 4; ++i) {
        const int ai = wv * 4 + i;                 // 0..15, 1KB each -> A 16KB
        const int ra = ai * 8 + (lane >> 3);       // row 0..127
        const int ua = lane & 7;                   // 16B unit in 128B row
        aoff[i] = (bm * 128 + ra) * (DIM * 4) + bz * (ksplit * 4)
                + ((ua ^ (ra & 7)) * 16);
        ldsA[i] = ai * 1024;                       // wave-uniform dest (HW adds lane*16)
        const int wi_ = wv * 4 + i;                // 0..15 -> W 16KB
        const int p = wi_ >> 3;                    // plane
        const int rw = (wi_ & 7) * 16 + (lane >> 2);  // row 0..127
        const int uw = lane & 3;                   // 16B unit in 64B row
        woff[i] = p * WPLANE_BYTES + (bn * 128 + rw) * (DIM * 2) + bz * (ksplit * 2)
                + ((uw ^ ((rw >> 1) & 3)) * 16);
        ldsW[i] = 16384 + wi_ * 1024;
    }

    // ---- fragment-read byte offsets ----
    int rA[4][2], rW[4][2];
#pragma unroll
    for (int m = 0; m < 4; ++m) {
        const int r = wr * 64 + m * 16 + l15;
        rA[m][0] = r * 128 + (((2 * q4 + 0) ^ (r & 7)) * 16);
        rA[m][1] = r * 128 + (((2 * q4 + 1) ^ (r & 7)) * 16);
    }
#pragma unroll
    for (int n = 0; n < 4; ++n) {
        const int rw = wc * 64 + n * 16 + l15;
        rW[n][0] = 16384 + 0    + rw * 64 + ((q4 ^ ((rw >> 1) & 3)) * 16);
        rW[n][1] = 16384 + 8192 + rw * 64 + ((q4 ^ ((rw >> 1) & 3)) * 16);
    }

    f32x4 acc[4][4];
#pragma unroll
    for (int m = 0; m < 4; ++m)
#pragma unroll
        for (int n = 0; n < 4; ++n) acc[m][n] = (f32x4){0.f, 0.f, 0.f, 0.f};

#define STAGE(sb)                                                               \
    {                                                                           \
        _Pragma("unroll")                                                       \
        for (int i = 0; i < 4; ++i)                                             \
            __builtin_amdgcn_global_load_lds((const AS1 void*)(xc + aoff[i]),   \
                (AS3 void*)(smem + (sb) + ldsA[i]), 16, 0, 0);                  \
        _Pragma("unroll")                                                       \
        for (int i = 0; i < 4; ++i)                                             \
            __builtin_amdgcn_global_load_lds((const AS1 void*)(wcp + woff[i]),  \
                (AS3 void*)(smem + (sb) + ldsW[i]), 16, 0, 0);                  \
        _Pragma("unroll")                                                       \
        for (int i = 0; i < 4; ++i) { aoff[i] += 128; woff[i] += 64; }          \
    }

#define COMPUTE(sb)                                                             \
    {                                                                           \
        f16x8 bfr[4][2];                                                        \
        _Pragma("unroll")                                                       \
        for (int n = 0; n < 4; ++n) {                                           \
            bfr[n][0] = *(const f16x8*)(smem + (sb) + rW[n][0]);                \
            bfr[n][1] = *(const f16x8*)(smem + (sb) + rW[n][1]);                \
        }                                                                       \
        _Pragma("unroll")                                                       \
        for (int m = 0; m < 4; ++m) {                                           \
            const f32x4 v0 = *(const f32x4*)(smem + (sb) + rA[m][0]);           \
            const f32x4 v1 = *(const f32x4*)(smem + (sb) + rA[m][1]);           \
            float c[8] = {v0[0]*4096.f, v0[1]*4096.f, v0[2]*4096.f, v0[3]*4096.f,\
                          v1[0]*4096.f, v1[1]*4096.f, v1[2]*4096.f, v1[3]*4096.f};\
            f16x8 a0, a1;                                                       \
            _Pragma("unroll")                                                   \
            for (int j = 0; j < 4; ++j) {                                       \
                h16x2 hp = __builtin_amdgcn_cvt_pkrtz(c[2*j], c[2*j+1]);        \
                float r0 = c[2*j]   - (float)hp[0];                             \
                float r1 = c[2*j+1] - (float)hp[1];                             \
                h16x2 gp = __builtin_amdgcn_cvt_pkrtz(r0, r1);                  \
                a0[2*j] = (f16)hp[0]; a0[2*j+1] = (f16)hp[1];                   \
                a1[2*j] = (f16)gp[0]; a1[2*j+1] = (f16)gp[1];                   \
            }                                                                   \
            __builtin_amdgcn_s_setprio(1);                                      \
            _Pragma("unroll")                                                   \
            for (int n = 0; n < 4; ++n) {                                       \
                acc[m][n] = __builtin_amdgcn_mfma_f32_16x16x32_f16(a0, bfr[n][0], acc[m][n], 0, 0, 0); \
                acc[m][n] = __builtin_amdgcn_mfma_f32_16x16x32_f16(a1, bfr[n][0], acc[m][n], 0, 0, 0); \
                acc[m][n] = __builtin_amdgcn_mfma_f32_16x16x32_f16(a0, bfr[n][1], acc[m][n], 0, 0, 0); \
                acc[m][n] = __builtin_amdgcn_mfma_f32_16x16x32_f16(a1, bfr[n][1], acc[m][n], 0, 0, 0); \
            }                                                                   \
            __builtin_amdgcn_s_setprio(0);                                      \
        }                                                                       \
    }

    const int niter = ksplit >> 5;   // 56 (nsplit=4) or 112 (nsplit=2)
    STAGE(0);                        // prologue: K-step 0 -> buf0
    for (int t = 0; t < niter - 1; ++t) {
        const int cur = (t & 1) * 32768;
        const int nxt = ((t + 1) & 1) * 32768;
        STAGE(nxt);                                  // 8 loads in flight across barrier
        asm volatile("s_waitcnt vmcnt(8)" ::: "memory");   // wait only K-step t's loads
        __builtin_amdgcn_sched_barrier(0);
        __builtin_amdgcn_s_barrier();                // buf[cur] fully populated
        COMPUTE(cur);
        __builtin_amdgcn_s_barrier();                // all reads of buf[cur] done
    }
    asm volatile("s_waitcnt vmcnt(0)" ::: "memory");
    __builtin_amdgcn_sched_barrier(0);
    __builtin_amdgcn_s_barrier();
    COMPUTE(((niter - 1) & 1) * 32768);
#undef STAGE
#undef COMPUTE

    // epilogue: store raw scaled partials (routing applies 2^-24)
    float* P = part + (size_t)bz * T_TOKENS * NEXP;
    const int orow = bm * 128 + wr * 64 + (lane >> 4) * 4;
    const int ocol = bn * 128 + wc * 64 + l15;
#pragma unroll
    for (int m = 0; m < 4; ++m)
#pragma unroll
        for (int n = 0; n < 4; ++n)
#pragma unroll
            for (int r = 0; r < 4; ++r)
                P[(size_t)(orow + m * 16 + r) * NEXP + ocol + n * 16] = acc[m][n][r];
}

// ---------------- Routing: one wave per token (identical logic to R3) ----------------
__global__ __launch_bounds__(256) void routing_kernel(const float* __restrict__ part,
                                                      const float* __restrict__ bias,
                                                      float* __restrict__ out, int nsplit) {
    const int lane = threadIdx.x & 63;
    const int t = blockIdx.x * 4 + (threadIdx.x >> 6);

    f32x4 z = {0.f, 0.f, 0.f, 0.f};
    for (int s = 0; s < nsplit; ++s) {
        const f32x4 v = *((const f32x4*)(part + ((size_t)s * T_TOKENS + t) * NEXP) + lane);
        z[0] += v[0]; z[1] += v[1]; z[2] += v[2]; z[3] += v[3];
    }
    const float s0 = 1.0f / (1.0f + expf(-z[0] * UNSCALE));
    const float s1 = 1.0f / (1.0f + expf(-z[1] * UNSCALE));
    const float s2 = 1.0f / (1.0f + expf(-z[2] * UNSCALE));
    const float s3 = 1.0f / (1.0f + expf(-z[3] * UNSCALE));
    const f32x4 bv = *((const f32x4*)bias + lane);
    float sb0 = s0 + bv[0], sb1 = s1 + bv[1], sb2 = s2 + bv[2], sb3 = s3 + bv[3];

    float m1, m2;
    m1 = sb0; m2 = NEG_INF;
    if (sb1 > m1) { m2 = m1; m1 = sb1; } else if (sb1 > m2) m2 = sb1;
    if (sb2 > m1) { m2 = m1; m1 = sb2; } else if (sb2 > m2) m2 = sb2;
    if (sb3 > m1) { m2 = m1; m1 = sb3; } else if (sb3 > m2) m2 = sb3;
#pragma unroll
    for (int off = 1; off < 8; off <<= 1) {
        const float om1 = __shfl_xor(m1, off);
        const float om2 = __shfl_xor(m2, off);
        const float hi = fmaxf(m1, om1);
        const float lo = fminf(m1, om1);
        m2 = fmaxf(lo, fmaxf(m2, om2));
        m1 = hi;
    }
    const float gs = m1 + m2;

    const float g0 = __shfl(gs, 0),  g1 = __shfl(gs, 8),  g2 = __shfl(gs, 16), g3 = __shfl(gs, 24);
    const float g4 = __shfl(gs, 32), g5 = __shfl(gs, 40), g6 = __shfl(gs, 48), g7 = __shfl(gs, 56);

    float t1 = NEG_INF, t2 = NEG_INF, t3 = NEG_INF, t4 = NEG_INF;
    int i1 = 0, i2 = 0, i3 = 0, i4 = 0;
#define INS4(v, gi)                                                         \
    {                                                                       \
        if (v > t1)      { t4=t3;i4=i3; t3=t2;i3=i2; t2=t1;i2=i1; t1=v;i1=gi; } \
        else if (v > t2) { t4=t3;i4=i3; t3=t2;i3=i2; t2=v;i2=gi; }          \
        else if (v > t3) { t4=t3;i4=i3; t3=v;i3=gi; }                       \
        else if (v > t4) { t4=v;i4=gi; }                                    \
    }
    INS4(g0, 0) INS4(g1, 1) INS4(g2, 2) INS4(g3, 3)
    INS4(g4, 4) INS4(g5, 5) INS4(g6, 6) INS4(g7, 7)
#undef INS4
    const int keepmask = (1 << i1) | (1 << i2) | (1 << i3) | (1 << i4);

    const int g = lane >> 3;
    if (!((keepmask >> g) & 1)) { sb0 = NEG_INF; sb1 = NEG_INF; sb2 = NEG_INF; sb3 = NEG_INF; }

    float wval[8];
    int wi[8];
    float wsum = 0.0f;
#pragma unroll
    for (int r = 0; r < 8; r++) {
        float bvv = sb0;
        int bii = (lane << 2);
        if (sb1 > bvv) { bvv = sb1; bii = (lane << 2) | 1; }
        if (sb2 > bvv) { bvv = sb2; bii = (lane << 2) | 2; }
        if (sb3 > bvv) { bvv = sb3; bii = (lane << 2) | 3; }
#pragma unroll
        for (int off = 1; off < 64; off <<= 1) {
            const float ov = __shfl_xor(bvv, off);
            const int oi = __shfl_xor(bii, off);
            if (ov > bvv || (ov == bvv && oi < bii)) { bvv = ov; bii = oi; }
        }
        const int sl = bii & 3;
        const float cand = (sl == 0) ? s0 : (sl == 1) ? s1 : (sl == 2) ? s2 : s3;
        const float ow = __shfl(cand, bii >> 2);
        wval[r] = ow;
        wi[r] = bii;
        wsum += ow;
        if ((bii >> 2) == lane) {
            if (sl == 0) sb0 = NEG_INF;
            else if (sl == 1) sb1 = NEG_INF;
            else if (sl == 2) sb2 = NEG_INF;
            else sb3 = NEG_INF;
        }
    }
    const float scale = 2.5f / wsum;
    if (lane == 0) {
        float* ow8 = out + (size_t)t * 8;
        float* oi8 = out + (size_t)T_TOKENS * 8 + (size_t)t * 8;
#pragma unroll
        for (int r = 0; r < 8; r++) {
            ow8[r] = wval[r] * scale;
            oi8[r] = (float)wi[r];
        }
    }
}

extern "C" void kernel_launch(void* const* d_in, const int* in_sizes, int n_in,
                              void* d_out, int out_size, void* d_ws, size_t ws_size,
                              hipStream_t stream) {
    const float* x = (const float*)d_in[0];
    const float* w = (const float*)d_in[1];
    const float* bias = (const float*)d_in[2];

    f16* w0 = (f16*)d_ws;
    f16* w1 = (f16*)((char*)d_ws + WPLANE_BYTES);
    float* part = (float*)((char*)d_ws + PART_OFF);

    const size_t need4 = (size_t)PART_OFF + 4ull * T_TOKENS * NEXP * 4;
    const int nsplit = (ws_size >= need4) ? 4 : 2;
    const int ksplit = DIM / nsplit;

    wconvert<<<NEXP * DIM / (256 * 8), 256, 0, stream>>>(w, w0, w1);
    gemm_f16split_db<<<dim3(64, 2, nsplit), 256, 0, stream>>>(x, w0, part, ksplit);
    routing_kernel<<<T_TOKENS / 4, 256, 0, stream>>>(part, bias, (float*)d_out, nsplit);
}